// Round 5
// baseline (22393.071 us; speedup 1.0000x reference)
//
#include <hip/hip_runtime.h>
#include <hip/hip_cooperative_groups.h>

namespace cg = cooperative_groups;

typedef unsigned int uint32;
typedef _Float16 f16;
typedef _Float16 half8 __attribute__((ext_vector_type(8)));
typedef float floatx4 __attribute__((ext_vector_type(4)));

#define HD    512    // hidden
#define NBAT  256    // batch
#define CTXL  512    // context length
#define NPRED 64     // prediction length
#define NBLK  256
#define NTHR  256
#define LDS_LD 520               // padded f16 leading dim (2-way bank alias only)
#define LDS_BYTES (96*LDS_LD*2)  // 99840 B

// Scratch in device globals (no d_ws dependence). Everything is fully
// (re)written by the kernel each launch before any read of it.
__device__ __attribute__((aligned(256))) f16   g_h0[2][NBAT][HD];   // layer-0 hidden, dbuf
__device__ __attribute__((aligned(256))) f16   g_h1[2][NBAT][HD];   // layer-1 hidden, dbuf
__device__ __attribute__((aligned(256))) float g_yacc[NPRED][NBAT]; // raw (unscaled) forecasts
__device__ __attribute__((aligned(256))) float g_scale[NBAT];

__device__ __forceinline__ float sigm(float x){ return 1.f/(1.f+__expf(-x)); }
__device__ __forceinline__ float tanh_(float x){ return 1.f - 2.f/(__expf(2.f*x)+1.f); }

// Persistent 2-layer GRU + AR decode (cooperative launch, grid.sync barriers).
// A-blocks (0..127): layer 0.  8 M-groups x 32 batch rows, 16 N-groups x 32 hidden cols.
//   LDS: Whh0 rows {r,z,n} x 32 cols (96 rows x 512), f16.
// B-blocks (128..255): layer 1. 4 M-groups x 64 rows, 32 N-groups x 16 hidden cols.
//   LDS: Wih1 (48 rows) + Whh1 (48 rows), f16.
// Interval i: A does layer-0 step i (enc); B does layer-1 step i-1.
// Decode step d: A at interval 513+2d, B at 514+2d.
__global__ __launch_bounds__(NTHR, 1) void rnn_persist(
    const float* __restrict__ ctx,    // [256][512] f32
    const float* __restrict__ Wih0,   // [1536] f32 (input size 1)
    const float* __restrict__ Whh0,   // [1536][512] f32
    const float* __restrict__ bih0,   // [1536]
    const float* __restrict__ bhh0,   // [1536]
    const float* __restrict__ Wih1,   // [1536][512]
    const float* __restrict__ Whh1,   // [1536][512]
    const float* __restrict__ bih1,   // [1536]
    const float* __restrict__ bhh1,   // [1536]
    const float* __restrict__ Wout,   // [512]
    const float* __restrict__ boutp,  // [1]
    float* __restrict__ out)          // [256][64] f32
{
  cg::grid_group grid = cg::this_grid();
  extern __shared__ char smem_raw[];
  f16* wlds = (f16*)smem_raw;
  __shared__ float wsum[4];

  const int tid  = threadIdx.x;
  const int bid  = blockIdx.x;
  const bool isA = bid < 128;
  const int w    = tid >> 6;
  const int lane = tid & 63;
  const int quad = lane >> 4;
  const int l16  = lane & 15;

  // ---------------- init: scale, zero BOTH h bufs + y_acc -------------------
  {
    const int b = bid; // block b handles batch row b
    float s2 = 0.f;
    for (int k = tid; k < CTXL; k += NTHR) s2 += ctx[b*CTXL + k];
    #pragma unroll
    for (int m = 1; m < 64; m <<= 1) s2 += __shfl_xor(s2, m, 64);
    if (lane == 0) wsum[w] = s2;
    __syncthreads();
    float tot = wsum[0] + wsum[1] + wsum[2] + wsum[3];
    float sc  = fmaxf(fabsf(tot / (float)CTXL), 1e-5f);
    if (tid == 0) g_scale[b] = sc;
    for (int k = tid; k < HD; k += NTHR) {
      g_h0[0][b][k] = (f16)0.f; g_h0[1][b][k] = (f16)0.f;
      g_h1[0][b][k] = (f16)0.f; g_h1[1][b][k] = (f16)0.f;
    }
    float* yflat = &g_yacc[0][0];
    for (int k = tid; k < 64; k += NTHR) yflat[b*64 + k] = 0.f;
  }

  // ---------------- weight slices -> LDS (f32 -> f16) -----------------------
  int Mbase, s0;
  if (isA) {
    const int mg = bid >> 4, ng = bid & 15;
    Mbase = mg * 32; s0 = ng * 32;
    for (int idx = tid; idx < 96*512; idx += NTHR) {
      int r = idx >> 9, k = idx & 511;
      int g = r >> 5, jj = r & 31;
      wlds[r*LDS_LD + k] = (f16)Whh0[(g*HD + s0 + jj)*HD + k];
    }
  } else {
    const int bid2 = bid - 128;
    const int mg = bid2 >> 5, ng = bid2 & 31;
    Mbase = mg * 64; s0 = ng * 16;
    for (int idx = tid; idx < 96*512; idx += NTHR) {
      int r = idx >> 9, k = idx & 511;
      const float* Wsrc = (r < 48) ? Wih1 : Whh1;
      int rr = (r < 48) ? r : r - 48;
      int g = rr >> 4, jj = rr & 15;
      wlds[r*LDS_LD + k] = (f16)Wsrc[(g*HD + s0 + jj)*HD + k];
    }
  }

  // ---------------- per-thread constants ------------------------------------
  float wi_r=0, wi_z=0, wi_n=0, bi_r, bi_z, bi_n, bh_r, bh_z, bh_n;
  float woutj=0, boutv=0;
  int jcol, mf;
  if (isA) {
    mf = w >> 1; const int jh = w & 1;
    jcol = s0 + jh*16 + l16;
    wi_r = Wih0[jcol]; wi_z = Wih0[HD + jcol]; wi_n = Wih0[2*HD + jcol];
    bi_r = bih0[jcol]; bi_z = bih0[HD + jcol]; bi_n = bih0[2*HD + jcol];
    bh_r = bhh0[jcol]; bh_z = bhh0[HD + jcol]; bh_n = bhh0[2*HD + jcol];
  } else {
    mf = w; jcol = s0 + l16;
    bi_r = bih1[jcol]; bi_z = bih1[HD + jcol]; bi_n = bih1[2*HD + jcol];
    bh_r = bhh1[jcol]; bh_z = bhh1[HD + jcol]; bh_n = bhh1[2*HD + jcol];
    woutj = Wout[jcol]; boutv = boutp[0];
  }

  grid.sync();   // scale, h bufs, y_acc, LDS weights all ready

  // A-threads: preload scale for their 4 output rows (stable after sync)
  float scl[4] = {1.f,1.f,1.f,1.f};
  if (isA) {
    const int bb = Mbase + mf*16 + quad*4;
    #pragma unroll
    for (int reg = 0; reg < 4; ++reg) scl[reg] = g_scale[bb + reg];
  }

  // ---------------- interval loop -------------------------------------------
  for (int i = 0; i <= 638; ++i) {
    if (isA) {
      int sA = -1;
      if (i <= 511) sA = i;
      else if (i >= 513 && ((i-513)&1) == 0 && (i-513)/2 <= 62)
        sA = 512 + (i-513)/2;
      if (sA >= 0) {
        const f16* hrd = &g_h0[sA & 1][0][0];
        f16*       hwr = &g_h0[(sA+1) & 1][0][0];
        floatx4 ar = {0.f,0.f,0.f,0.f}, az = ar, an_ = ar;
        const int arow = Mbase + mf*16 + l16;
        const f16* aptr = hrd + (size_t)arow*HD + quad*8;
        const f16* b_r  = wlds + (size_t)((w&1)*16 + l16)*LDS_LD + quad*8;
        #pragma unroll 4
        for (int kc = 0; kc < 16; ++kc) {
          half8 a  = *(const half8*)(aptr + kc*32);
          half8 vr = *(const half8*)(b_r + kc*32);
          half8 vz = *(const half8*)(b_r + 32*LDS_LD + kc*32);
          half8 vn = *(const half8*)(b_r + 64*LDS_LD + kc*32);
          ar  = __builtin_amdgcn_mfma_f32_16x16x32_f16(a, vr, ar,  0,0,0);
          az  = __builtin_amdgcn_mfma_f32_16x16x32_f16(a, vz, az,  0,0,0);
          an_ = __builtin_amdgcn_mfma_f32_16x16x32_f16(a, vn, an_, 0,0,0);
        }
        #pragma unroll
        for (int reg = 0; reg < 4; ++reg) {
          const int b = Mbase + mf*16 + quad*4 + reg;
          float x = (sA < 512) ? (ctx[b*CTXL + sA] / scl[reg])
                               : g_yacc[sA-512][b];
          float hgr = ar[reg] + bh_r, hgz = az[reg] + bh_z, hgn = an_[reg] + bh_n;
          float rg  = sigm(fmaf(x, wi_r, bi_r) + hgr);
          float zg  = sigm(fmaf(x, wi_z, bi_z) + hgz);
          float ng_ = tanh_(fmaf(x, wi_n, bi_n) + rg*hgn);
          float hold = (float)hrd[(size_t)b*HD + jcol];
          hwr[(size_t)b*HD + jcol] = (f16)((1.f - zg)*ng_ + zg*hold);
        }
      }
    } else {
      int sB = -1;
      if (i >= 1 && i <= 512) sB = i - 1;
      else if (i >= 514 && ((i-514)&1) == 0 && (i-514)/2 <= 62)
        sB = 512 + (i-514)/2;
      if (sB >= 0) {
        const f16* h0rd = &g_h0[(sB+1) & 1][0][0];   // layer-0 output of step sB
        const f16* h1rd = &g_h1[sB & 1][0][0];
        f16*       h1wr = &g_h1[(sB+1) & 1][0][0];
        floatx4 xr = {0.f,0.f,0.f,0.f}, xz = xr, xn = xr, hr = xr, hz = xr, hn = xr;
        const int arow = Mbase + mf*16 + l16;
        const f16* a0p = h0rd + (size_t)arow*HD + quad*8;
        const f16* a1p = h1rd + (size_t)arow*HD + quad*8;
        const f16* bw  = wlds + (size_t)l16*LDS_LD + quad*8;
        #pragma unroll 4
        for (int kc = 0; kc < 16; ++kc) {
          half8 a0 = *(const half8*)(a0p + kc*32);
          half8 a1 = *(const half8*)(a1p + kc*32);
          half8 v;
          v = *(const half8*)(bw +             kc*32); xr = __builtin_amdgcn_mfma_f32_16x16x32_f16(a0, v, xr, 0,0,0);
          v = *(const half8*)(bw + 16*LDS_LD + kc*32); xz = __builtin_amdgcn_mfma_f32_16x16x32_f16(a0, v, xz, 0,0,0);
          v = *(const half8*)(bw + 32*LDS_LD + kc*32); xn = __builtin_amdgcn_mfma_f32_16x16x32_f16(a0, v, xn, 0,0,0);
          v = *(const half8*)(bw + 48*LDS_LD + kc*32); hr = __builtin_amdgcn_mfma_f32_16x16x32_f16(a1, v, hr, 0,0,0);
          v = *(const half8*)(bw + 64*LDS_LD + kc*32); hz = __builtin_amdgcn_mfma_f32_16x16x32_f16(a1, v, hz, 0,0,0);
          v = *(const half8*)(bw + 80*LDS_LD + kc*32); hn = __builtin_amdgcn_mfma_f32_16x16x32_f16(a1, v, hn, 0,0,0);
        }
        #pragma unroll
        for (int reg = 0; reg < 4; ++reg) {
          const int b = Mbase + mf*16 + quad*4 + reg;
          float rg  = sigm(xr[reg] + bi_r + hr[reg] + bh_r);
          float zg  = sigm(xz[reg] + bi_z + hz[reg] + bh_z);
          float ng_ = tanh_(xn[reg] + bi_n + rg*(hn[reg] + bh_n));
          float hold = (float)h1rd[(size_t)b*HD + jcol];
          float hnew = (1.f - zg)*ng_ + zg*hold;
          h1wr[(size_t)b*HD + jcol] = (f16)hnew;
          if (sB >= 511) {                       // emit forecast partials
            float c = hnew * woutj;
            c += __shfl_xor(c, 1, 64); c += __shfl_xor(c, 2, 64);
            c += __shfl_xor(c, 4, 64); c += __shfl_xor(c, 8, 64);
            if (l16 == 0) {
              if (s0 == 0) c += boutv;           // bias exactly once per row
              atomicAdd(&g_yacc[sB-511][b], c);
            }
          }
        }
      }
    }
    grid.sync();
  }

  // ---------------- output: forecast[b][p] = y_raw[p][b] * scale[b] ---------
  if (bid < NPRED) {
    const int p = bid;
    for (int b = tid; b < NBAT; b += NTHR)
      out[b*NPRED + p] = g_yacc[p][b] * g_scale[b];
  }
}

extern "C" void kernel_launch(void* const* d_in, const int* in_sizes, int n_in,
                              void* d_out, int out_size, void* d_ws, size_t ws_size,
                              hipStream_t stream) {
  const float* ctx   = (const float*)d_in[0];
  const float* Wih0  = (const float*)d_in[1];
  const float* Whh0  = (const float*)d_in[2];
  const float* bih0  = (const float*)d_in[3];
  const float* bhh0  = (const float*)d_in[4];
  const float* Wih1  = (const float*)d_in[5];
  const float* Whh1  = (const float*)d_in[6];
  const float* bih1  = (const float*)d_in[7];
  const float* bhh1  = (const float*)d_in[8];
  const float* Wout  = (const float*)d_in[9];
  const float* boutp = (const float*)d_in[10];
  float* out = (float*)d_out;

  hipFuncSetAttribute(reinterpret_cast<const void*>(rnn_persist),
                      hipFuncAttributeMaxDynamicSharedMemorySize, LDS_BYTES);

  void* params[] = {
    (void*)&ctx, (void*)&Wih0, (void*)&Whh0, (void*)&bih0, (void*)&bhh0,
    (void*)&Wih1, (void*)&Whh1, (void*)&bih1, (void*)&bhh1,
    (void*)&Wout, (void*)&boutp, (void*)&out
  };
  hipLaunchCooperativeKernel(reinterpret_cast<void*>(rnn_persist),
                             dim3(NBLK), dim3(NTHR), params, LDS_BYTES, stream);
}

// Round 6
// 13478.503 us; speedup vs baseline: 1.6614x; 1.6614x over previous
//
#include <hip/hip_runtime.h>
#include <hip/hip_cooperative_groups.h>

namespace cg = cooperative_groups;

typedef unsigned int uint32;
typedef _Float16 f16;
typedef _Float16 half8 __attribute__((ext_vector_type(8)));
typedef float floatx4 __attribute__((ext_vector_type(4)));

#define HD    512    // hidden
#define NBAT  256    // batch
#define CTXL  512    // context length
#define NPRED 64     // prediction length
#define NBLK  256
#define NTHR  256
#define LDS_LD 520               // padded f16 leading dim (2-way bank alias only)
#define LDS_BYTES (96*LDS_LD*2)  // 99840 B
#define NGEN  640u               // grid barriers per launch

// Scratch in device globals. ALL cross-block data goes through relaxed
// agent-scope atomics (sc1 path -> memory-side L3, coherent across XCDs,
// NO L2 flushes). h kept f16 for MFMA fragments.
__device__ __attribute__((aligned(256))) f16   g_h0[2][NBAT][HD];
__device__ __attribute__((aligned(256))) f16   g_h1[2][NBAT][HD];
__device__ __attribute__((aligned(256))) float g_yacc[NPRED][NBAT];
__device__ __attribute__((aligned(256))) float g_scale[NBAT];
__device__ __attribute__((aligned(256))) uint32 g_ctr;    // monotonic barrier counter
__device__ __attribute__((aligned(256))) uint32 g_epoch;  // counter base across launches

__device__ __forceinline__ float sigm(float x){ return 1.f/(1.f+__expf(-x)); }
__device__ __forceinline__ float tanh_(float x){ return 1.f - 2.f/(__expf(2.f*x)+1.f); }

// ---- sc1 (device-coherent, no-flush) access helpers ------------------------
__device__ __forceinline__ uint32 ld_u32_dc(const uint32* p){
  return __hip_atomic_load(p, __ATOMIC_RELAXED, __HIP_MEMORY_SCOPE_AGENT);
}
__device__ __forceinline__ void st_u32_dc(uint32* p, uint32 v){
  __hip_atomic_store(p, v, __ATOMIC_RELAXED, __HIP_MEMORY_SCOPE_AGENT);
}
__device__ __forceinline__ float ld_f32_dc(const float* p){
  return __hip_atomic_load(p, __ATOMIC_RELAXED, __HIP_MEMORY_SCOPE_AGENT);
}
__device__ __forceinline__ void st_f32_dc(float* p, float v){
  __hip_atomic_store(p, v, __ATOMIC_RELAXED, __HIP_MEMORY_SCOPE_AGENT);
}
__device__ __forceinline__ float ld_f16_dc(const f16* p){
  unsigned short u = __hip_atomic_load((const unsigned short*)p, __ATOMIC_RELAXED, __HIP_MEMORY_SCOPE_AGENT);
  union { unsigned short u; f16 h; } c; c.u = u; return (float)c.h;
}
__device__ __forceinline__ void st_f16_dc(f16* p, float x){
  union { unsigned short u; f16 h; } c; c.h = (f16)x;
  __hip_atomic_store((unsigned short*)p, c.u, __ATOMIC_RELAXED, __HIP_MEMORY_SCOPE_AGENT);
}
__device__ __forceinline__ half8 ld_half8_dc(const f16* p){
  const uint32* q = (const uint32*)p;
  union { uint32 u[4]; half8 h; } r;
  r.u[0] = ld_u32_dc(q+0); r.u[1] = ld_u32_dc(q+1);
  r.u[2] = ld_u32_dc(q+2); r.u[3] = ld_u32_dc(q+3);
  return r.h;
}

// Flat monotonic grid barrier: one agent-scope counter, no reset (epoch base),
// workgroup-scope release fence only (s_waitcnt, no cache flushes).
__device__ __forceinline__ void gbar(uint32 base, uint32 gen){
  __builtin_amdgcn_fence(__ATOMIC_RELEASE, "workgroup");  // drain my sc1 stores
  __syncthreads();
  if (threadIdx.x == 0){
    __hip_atomic_fetch_add(&g_ctr, 1u, __ATOMIC_RELAXED, __HIP_MEMORY_SCOPE_AGENT);
    const uint32 target = base + gen*(uint32)NBLK;
    uint32 v;
    do {
      __builtin_amdgcn_s_sleep(2);
      v = __hip_atomic_load(&g_ctr, __ATOMIC_RELAXED, __HIP_MEMORY_SCOPE_AGENT);
    } while ((int)(v - target) < 0);
  }
  __syncthreads();
}

// Persistent 2-layer GRU + AR decode.
// A-blocks (0..127): layer 0.  8 M-groups x 32 batch rows, 16 N-groups x 32 hidden cols.
// B-blocks (128..255): layer 1. 4 M-groups x 64 rows, 32 N-groups x 16 hidden cols.
// Interval i: A does layer-0 step i (enc); B does layer-1 step i-1.
// Decode step d: A at interval 513+2d, B at 514+2d.
__global__ __launch_bounds__(NTHR, 1) void rnn_persist(
    const float* __restrict__ ctx,    // [256][512] f32
    const float* __restrict__ Wih0,   // [1536]
    const float* __restrict__ Whh0,   // [1536][512]
    const float* __restrict__ bih0,   // [1536]
    const float* __restrict__ bhh0,   // [1536]
    const float* __restrict__ Wih1,   // [1536][512]
    const float* __restrict__ Whh1,   // [1536][512]
    const float* __restrict__ bih1,   // [1536]
    const float* __restrict__ bhh1,   // [1536]
    const float* __restrict__ Wout,   // [512]
    const float* __restrict__ boutp,  // [1]
    float* __restrict__ out)          // [256][64] f32
{
  extern __shared__ char smem_raw[];
  f16* wlds = (f16*)smem_raw;
  __shared__ float wsum[4];

  const int tid  = threadIdx.x;
  const int bid  = blockIdx.x;
  const bool isA = bid < 128;
  const int w    = tid >> 6;
  const int lane = tid & 63;
  const int quad = lane >> 4;
  const int l16  = lane & 15;

  const uint32 base = ld_u32_dc(&g_epoch);

  // ---------------- init: scale, zero h bufs + y_acc (all sc1) --------------
  {
    const int b = bid; // block b handles batch row b
    float s2 = 0.f;
    for (int k = tid; k < CTXL; k += NTHR) s2 += ctx[b*CTXL + k];
    #pragma unroll
    for (int m = 1; m < 64; m <<= 1) s2 += __shfl_xor(s2, m, 64);
    if (lane == 0) wsum[w] = s2;
    __syncthreads();
    float tot = wsum[0] + wsum[1] + wsum[2] + wsum[3];
    float sc  = fmaxf(fabsf(tot / (float)CTXL), 1e-5f);
    if (tid == 0) st_f32_dc(&g_scale[b], sc);
    // zero h (both buffers) as dwords: 256 dwords per [b] row per buffer
    uint32* h00 = (uint32*)&g_h0[0][b][0]; uint32* h01 = (uint32*)&g_h0[1][b][0];
    uint32* h10 = (uint32*)&g_h1[0][b][0]; uint32* h11 = (uint32*)&g_h1[1][b][0];
    for (int k = tid; k < HD/2; k += NTHR) {
      st_u32_dc(h00+k, 0u); st_u32_dc(h01+k, 0u);
      st_u32_dc(h10+k, 0u); st_u32_dc(h11+k, 0u);
    }
    float* yflat = &g_yacc[0][0];
    for (int k = tid; k < 64; k += NTHR) st_f32_dc(&yflat[b*64 + k], 0.f);
  }

  // ---------------- weight slices -> LDS (f32 -> f16) -----------------------
  int Mbase, s0;
  if (isA) {
    const int mg = bid >> 4, ng = bid & 15;
    Mbase = mg * 32; s0 = ng * 32;
    for (int idx = tid; idx < 96*512; idx += NTHR) {
      int r = idx >> 9, k = idx & 511;
      int g = r >> 5, jj = r & 31;
      wlds[r*LDS_LD + k] = (f16)Whh0[(g*HD + s0 + jj)*HD + k];
    }
  } else {
    const int bid2 = bid - 128;
    const int mg = bid2 >> 5, ng = bid2 & 31;
    Mbase = mg * 64; s0 = ng * 16;
    for (int idx = tid; idx < 96*512; idx += NTHR) {
      int r = idx >> 9, k = idx & 511;
      const float* Wsrc = (r < 48) ? Wih1 : Whh1;
      int rr = (r < 48) ? r : r - 48;
      int g = rr >> 4, jj = rr & 15;
      wlds[r*LDS_LD + k] = (f16)Wsrc[(g*HD + s0 + jj)*HD + k];
    }
  }

  // ---------------- per-thread constants ------------------------------------
  float wi_r=0, wi_z=0, wi_n=0, bi_r, bi_z, bi_n, bh_r, bh_z, bh_n;
  float woutj=0, boutv=0;
  int jcol, mf;
  if (isA) {
    mf = w >> 1; const int jh = w & 1;
    jcol = s0 + jh*16 + l16;
    wi_r = Wih0[jcol]; wi_z = Wih0[HD + jcol]; wi_n = Wih0[2*HD + jcol];
    bi_r = bih0[jcol]; bi_z = bih0[HD + jcol]; bi_n = bih0[2*HD + jcol];
    bh_r = bhh0[jcol]; bh_z = bhh0[HD + jcol]; bh_n = bhh0[2*HD + jcol];
  } else {
    mf = w; jcol = s0 + l16;
    bi_r = bih1[jcol]; bi_z = bih1[HD + jcol]; bi_n = bih1[2*HD + jcol];
    bh_r = bhh1[jcol]; bh_z = bhh1[HD + jcol]; bh_n = bhh1[2*HD + jcol];
    woutj = Wout[jcol]; boutv = boutp[0];
  }

  uint32 gen = 1;
  gbar(base, gen); gen++;   // scale, h bufs, y_acc, LDS weights all ready

  // A-threads: preload scale for their 4 output rows (stable after barrier 1)
  float scl[4] = {1.f,1.f,1.f,1.f};
  if (isA) {
    const int bb = Mbase + mf*16 + quad*4;
    #pragma unroll
    for (int reg = 0; reg < 4; ++reg) scl[reg] = ld_f32_dc(&g_scale[bb + reg]);
  }

  // ---------------- interval loop -------------------------------------------
  for (int i = 0; i <= 638; ++i) {
    if (isA) {
      int sA = -1;
      if (i <= 511) sA = i;
      else if (i >= 513 && ((i-513)&1) == 0 && (i-513)/2 <= 62)
        sA = 512 + (i-513)/2;
      if (sA >= 0) {
        const f16* hrd = &g_h0[sA & 1][0][0];
        f16*       hwr = &g_h0[(sA+1) & 1][0][0];
        floatx4 ar = {0.f,0.f,0.f,0.f}, az = ar, an_ = ar;
        const int arow = Mbase + mf*16 + l16;
        const f16* aptr = hrd + (size_t)arow*HD + quad*8;
        const f16* b_r  = wlds + (size_t)((w&1)*16 + l16)*LDS_LD + quad*8;
        #pragma unroll 4
        for (int kc = 0; kc < 16; ++kc) {
          half8 a  = ld_half8_dc(aptr + kc*32);
          half8 vr = *(const half8*)(b_r + kc*32);
          half8 vz = *(const half8*)(b_r + 32*LDS_LD + kc*32);
          half8 vn = *(const half8*)(b_r + 64*LDS_LD + kc*32);
          ar  = __builtin_amdgcn_mfma_f32_16x16x32_f16(a, vr, ar,  0,0,0);
          az  = __builtin_amdgcn_mfma_f32_16x16x32_f16(a, vz, az,  0,0,0);
          an_ = __builtin_amdgcn_mfma_f32_16x16x32_f16(a, vn, an_, 0,0,0);
        }
        #pragma unroll
        for (int reg = 0; reg < 4; ++reg) {
          const int b = Mbase + mf*16 + quad*4 + reg;
          float x = (sA < 512) ? (ctx[b*CTXL + sA] / scl[reg])
                               : ld_f32_dc(&g_yacc[sA-512][b]);
          float hgr = ar[reg] + bh_r, hgz = az[reg] + bh_z, hgn = an_[reg] + bh_n;
          float rg  = sigm(fmaf(x, wi_r, bi_r) + hgr);
          float zg  = sigm(fmaf(x, wi_z, bi_z) + hgz);
          float ng_ = tanh_(fmaf(x, wi_n, bi_n) + rg*hgn);
          float hold = ld_f16_dc(&hrd[(size_t)b*HD + jcol]);
          st_f16_dc(&hwr[(size_t)b*HD + jcol], (1.f - zg)*ng_ + zg*hold);
        }
      }
    } else {
      int sB = -1;
      if (i >= 1 && i <= 512) sB = i - 1;
      else if (i >= 514 && ((i-514)&1) == 0 && (i-514)/2 <= 62)
        sB = 512 + (i-514)/2;
      if (sB >= 0) {
        const f16* h0rd = &g_h0[(sB+1) & 1][0][0];   // layer-0 output of step sB
        const f16* h1rd = &g_h1[sB & 1][0][0];
        f16*       h1wr = &g_h1[(sB+1) & 1][0][0];
        floatx4 xr = {0.f,0.f,0.f,0.f}, xz = xr, xn = xr, hr = xr, hz = xr, hn = xr;
        const int arow = Mbase + mf*16 + l16;
        const f16* a0p = h0rd + (size_t)arow*HD + quad*8;
        const f16* a1p = h1rd + (size_t)arow*HD + quad*8;
        const f16* bw  = wlds + (size_t)l16*LDS_LD + quad*8;
        #pragma unroll 4
        for (int kc = 0; kc < 16; ++kc) {
          half8 a0 = ld_half8_dc(a0p + kc*32);
          half8 a1 = ld_half8_dc(a1p + kc*32);
          half8 v;
          v = *(const half8*)(bw +             kc*32); xr = __builtin_amdgcn_mfma_f32_16x16x32_f16(a0, v, xr, 0,0,0);
          v = *(const half8*)(bw + 16*LDS_LD + kc*32); xz = __builtin_amdgcn_mfma_f32_16x16x32_f16(a0, v, xz, 0,0,0);
          v = *(const half8*)(bw + 32*LDS_LD + kc*32); xn = __builtin_amdgcn_mfma_f32_16x16x32_f16(a0, v, xn, 0,0,0);
          v = *(const half8*)(bw + 48*LDS_LD + kc*32); hr = __builtin_amdgcn_mfma_f32_16x16x32_f16(a1, v, hr, 0,0,0);
          v = *(const half8*)(bw + 64*LDS_LD + kc*32); hz = __builtin_amdgcn_mfma_f32_16x16x32_f16(a1, v, hz, 0,0,0);
          v = *(const half8*)(bw + 80*LDS_LD + kc*32); hn = __builtin_amdgcn_mfma_f32_16x16x32_f16(a1, v, hn, 0,0,0);
        }
        #pragma unroll
        for (int reg = 0; reg < 4; ++reg) {
          const int b = Mbase + mf*16 + quad*4 + reg;
          float rg  = sigm(xr[reg] + bi_r + hr[reg] + bh_r);
          float zg  = sigm(xz[reg] + bi_z + hz[reg] + bh_z);
          float ng_ = tanh_(xn[reg] + bi_n + rg*(hn[reg] + bh_n));
          float hold = ld_f16_dc(&h1rd[(size_t)b*HD + jcol]);
          float hnew = (1.f - zg)*ng_ + zg*hold;
          st_f16_dc(&h1wr[(size_t)b*HD + jcol], hnew);
          if (sB >= 511) {                       // emit forecast partials
            float c = hnew * woutj;
            c += __shfl_xor(c, 1, 64); c += __shfl_xor(c, 2, 64);
            c += __shfl_xor(c, 4, 64); c += __shfl_xor(c, 8, 64);
            if (l16 == 0) {
              if (s0 == 0) c += boutv;           // bias exactly once per row
              atomicAdd(&g_yacc[sB-511][b], c);  // device-scope, sc1 path
            }
          }
        }
      }
    }
    gbar(base, gen); gen++;
  }

  // ---------------- epoch advance + output ----------------------------------
  if (bid == 0 && tid == 0)
    st_u32_dc(&g_epoch, base + NGEN*(uint32)NBLK);

  if (bid < NPRED) {
    const int p = bid;
    for (int b = tid; b < NBAT; b += NTHR)
      out[b*NPRED + p] = ld_f32_dc(&g_yacc[p][b]) * ld_f32_dc(&g_scale[b]);
  }
}

extern "C" void kernel_launch(void* const* d_in, const int* in_sizes, int n_in,
                              void* d_out, int out_size, void* d_ws, size_t ws_size,
                              hipStream_t stream) {
  const float* ctx   = (const float*)d_in[0];
  const float* Wih0  = (const float*)d_in[1];
  const float* Whh0  = (const float*)d_in[2];
  const float* bih0  = (const float*)d_in[3];
  const float* bhh0  = (const float*)d_in[4];
  const float* Wih1  = (const float*)d_in[5];
  const float* Whh1  = (const float*)d_in[6];
  const float* bih1  = (const float*)d_in[7];
  const float* bhh1  = (const float*)d_in[8];
  const float* Wout  = (const float*)d_in[9];
  const float* boutp = (const float*)d_in[10];
  float* out = (float*)d_out;

  hipFuncSetAttribute(reinterpret_cast<const void*>(rnn_persist),
                      hipFuncAttributeMaxDynamicSharedMemorySize, LDS_BYTES);

  void* params[] = {
    (void*)&ctx, (void*)&Wih0, (void*)&Whh0, (void*)&bih0, (void*)&bhh0,
    (void*)&Wih1, (void*)&Whh1, (void*)&bih1, (void*)&bhh1,
    (void*)&Wout, (void*)&boutp, (void*)&out
  };
  hipLaunchCooperativeKernel(reinterpret_cast<void*>(rnn_persist),
                             dim3(NBLK), dim3(NTHR), params, LDS_BYTES, stream);
}

// Round 7
// 6854.961 us; speedup vs baseline: 3.2667x; 1.9662x over previous
//
#include <hip/hip_runtime.h>

typedef unsigned int uint32;
typedef unsigned long long uint64;
typedef _Float16 f16;
typedef _Float16 half8 __attribute__((ext_vector_type(8)));
typedef float floatx4 __attribute__((ext_vector_type(4)));

#define HD    512    // hidden
#define NBAT  256    // batch
#define CTXL  512    // context length
#define NPRED 64     // prediction length
#define NBLK  256
#define NTHR  256
#define LDS_LD 520               // padded f16 leading dim (2-way bank alias only)
#define LDS_BYTES (96*LDS_LD*2)  // 99840 B
#define NGEN  640u               // grid barriers per launch

// Scratch in device globals. ALL cross-block data goes through relaxed
// agent-scope atomics (device-coherent path -> memory-side L3, shared by all
// XCDs, NO cache flushes anywhere).
__device__ __attribute__((aligned(256))) f16   g_h0[2][NBAT][HD];
__device__ __attribute__((aligned(256))) f16   g_h1[2][NBAT][HD];
__device__ __attribute__((aligned(256))) float g_yacc[NPRED][NBAT];
__device__ __attribute__((aligned(256))) float g_scale[NBAT];
// Tree-barrier state: 16 leaf-arrive lines, root, root-release, 16 leaf-release
__device__ __attribute__((aligned(256))) uint32 g_leaf_arr[16*16]; // stride 64B
__device__ __attribute__((aligned(256))) uint32 g_root_arr;
__device__ __attribute__((aligned(256))) uint32 g_root_rel;
__device__ __attribute__((aligned(256))) uint32 g_leaf_rel[16*16]; // stride 64B
__device__ __attribute__((aligned(256))) uint32 g_epoch;           // launch count

__device__ __forceinline__ float sigm(float x){ return 1.f/(1.f+__expf(-x)); }
__device__ __forceinline__ float tanh_(float x){ return 1.f - 2.f/(__expf(2.f*x)+1.f); }

// ---- device-coherent (no-flush) access helpers -----------------------------
__device__ __forceinline__ uint32 ld_u32_dc(const uint32* p){
  return __hip_atomic_load(p, __ATOMIC_RELAXED, __HIP_MEMORY_SCOPE_AGENT);
}
__device__ __forceinline__ void st_u32_dc(uint32* p, uint32 v){
  __hip_atomic_store(p, v, __ATOMIC_RELAXED, __HIP_MEMORY_SCOPE_AGENT);
}
__device__ __forceinline__ void st_u64_dc(uint64* p, uint64 v){
  __hip_atomic_store(p, v, __ATOMIC_RELAXED, __HIP_MEMORY_SCOPE_AGENT);
}
__device__ __forceinline__ float ld_f32_dc(const float* p){
  return __hip_atomic_load(p, __ATOMIC_RELAXED, __HIP_MEMORY_SCOPE_AGENT);
}
__device__ __forceinline__ void st_f32_dc(float* p, float v){
  __hip_atomic_store(p, v, __ATOMIC_RELAXED, __HIP_MEMORY_SCOPE_AGENT);
}
__device__ __forceinline__ float ld_f16_dc(const f16* p){
  unsigned short u = __hip_atomic_load((const unsigned short*)p, __ATOMIC_RELAXED, __HIP_MEMORY_SCOPE_AGENT);
  union { unsigned short u; f16 h; } c; c.u = u; return (float)c.h;
}
__device__ __forceinline__ void st_f16_dc(f16* p, float x){
  union { unsigned short u; f16 h; } c; c.h = (f16)x;
  __hip_atomic_store((unsigned short*)p, c.u, __ATOMIC_RELAXED, __HIP_MEMORY_SCOPE_AGENT);
}
__device__ __forceinline__ half8 ld_half8_dc(const f16* p){   // 2x b64 coherent loads
  const uint64* q = (const uint64*)p;
  union { uint64 u[2]; half8 h; } r;
  r.u[0] = __hip_atomic_load(q+0, __ATOMIC_RELAXED, __HIP_MEMORY_SCOPE_AGENT);
  r.u[1] = __hip_atomic_load(q+1, __ATOMIC_RELAXED, __HIP_MEMORY_SCOPE_AGENT);
  return r.h;
}

// Hierarchical monotonic grid barrier (16 leaves x 16 blocks, fan-in + fan-out).
// Max contention per line = 16. Counters never reset; epoch base per launch.
__device__ __forceinline__ void gbar(uint32 base16, uint32 baseRel, uint32 gen){
  __builtin_amdgcn_fence(__ATOMIC_RELEASE, "workgroup");  // drain my global stores (s_waitcnt only)
  __syncthreads();
  if (threadIdx.x == 0){
    const uint32 leaf = blockIdx.x >> 4;
    const uint32 tArr = base16 + gen*16u;
    const uint32 tRel = baseRel + gen;
    __hip_atomic_fetch_add(&g_leaf_arr[leaf*16], 1u, __ATOMIC_RELAXED, __HIP_MEMORY_SCOPE_AGENT);
    if ((blockIdx.x & 15) == 0){            // leaf leader
      while ((int)(ld_u32_dc(&g_leaf_arr[leaf*16]) - tArr) < 0) __builtin_amdgcn_s_sleep(1);
      __hip_atomic_fetch_add(&g_root_arr, 1u, __ATOMIC_RELAXED, __HIP_MEMORY_SCOPE_AGENT);
      if (blockIdx.x == 0){                 // root
        while ((int)(ld_u32_dc(&g_root_arr) - tArr) < 0) __builtin_amdgcn_s_sleep(1);
        __builtin_amdgcn_fence(__ATOMIC_RELEASE, "workgroup");
        st_u32_dc(&g_root_rel, tRel);
      } else {
        while ((int)(ld_u32_dc(&g_root_rel) - tRel) < 0) __builtin_amdgcn_s_sleep(1);
      }
      __builtin_amdgcn_fence(__ATOMIC_RELEASE, "workgroup");
      st_u32_dc(&g_leaf_rel[leaf*16], tRel);
    } else {                                // follower
      while ((int)(ld_u32_dc(&g_leaf_rel[leaf*16]) - tRel) < 0) __builtin_amdgcn_s_sleep(1);
    }
  }
  __syncthreads();
}

// Persistent 2-layer GRU + AR decode.
// A-blocks (0..127): layer 0.  8 M-groups x 32 batch rows, 16 N-groups x 32 hidden cols.
// B-blocks (128..255): layer 1. 4 M-groups x 64 rows, 32 N-groups x 16 hidden cols.
// Interval i: A does layer-0 step i (enc); B does layer-1 step i-1.
// Decode step d: A at interval 513+2d, B at 514+2d.
__global__ __launch_bounds__(NTHR, 1) void rnn_persist(
    const float* __restrict__ ctx,    // [256][512] f32
    const float* __restrict__ Wih0,   // [1536]
    const float* __restrict__ Whh0,   // [1536][512]
    const float* __restrict__ bih0,   // [1536]
    const float* __restrict__ bhh0,   // [1536]
    const float* __restrict__ Wih1,   // [1536][512]
    const float* __restrict__ Whh1,   // [1536][512]
    const float* __restrict__ bih1,   // [1536]
    const float* __restrict__ bhh1,   // [1536]
    const float* __restrict__ Wout,   // [512]
    const float* __restrict__ boutp,  // [1]
    float* __restrict__ out)          // [256][64] f32
{
  extern __shared__ char smem_raw[];
  f16* wlds = (f16*)smem_raw;
  __shared__ float wsum[4];

  const int tid  = threadIdx.x;
  const int bid  = blockIdx.x;
  const bool isA = bid < 128;
  const int w    = tid >> 6;
  const int lane = tid & 63;
  const int quad = lane >> 4;
  const int l16  = lane & 15;

  const uint32 E = ld_u32_dc(&g_epoch);
  const uint32 base16  = E * (NGEN*16u);
  const uint32 baseRel = E * NGEN;

  // ---------------- init: scale, zero h bufs + y_acc (coherent stores) ------
  {
    const int b = bid; // block b handles batch row b
    float s2 = 0.f;
    for (int k = tid; k < CTXL; k += NTHR) s2 += ctx[b*CTXL + k];
    #pragma unroll
    for (int m = 1; m < 64; m <<= 1) s2 += __shfl_xor(s2, m, 64);
    if (lane == 0) wsum[w] = s2;
    __syncthreads();
    float tot = wsum[0] + wsum[1] + wsum[2] + wsum[3];
    float sc  = fmaxf(fabsf(tot / (float)CTXL), 1e-5f);
    if (tid == 0) st_f32_dc(&g_scale[b], sc);
    uint64* h00 = (uint64*)&g_h0[0][b][0]; uint64* h01 = (uint64*)&g_h0[1][b][0];
    uint64* h10 = (uint64*)&g_h1[0][b][0]; uint64* h11 = (uint64*)&g_h1[1][b][0];
    for (int k = tid; k < HD/4; k += NTHR) {
      st_u64_dc(h00+k, 0ull); st_u64_dc(h01+k, 0ull);
      st_u64_dc(h10+k, 0ull); st_u64_dc(h11+k, 0ull);
    }
    float* yflat = &g_yacc[0][0];
    for (int k = tid; k < 64; k += NTHR) st_f32_dc(&yflat[b*64 + k], 0.f);
  }

  // ---------------- weight slices -> LDS (f32 -> f16) -----------------------
  int Mbase, s0;
  if (isA) {
    const int mg = bid >> 4, ng = bid & 15;
    Mbase = mg * 32; s0 = ng * 32;
    for (int idx = tid; idx < 96*512; idx += NTHR) {
      int r = idx >> 9, k = idx & 511;
      int g = r >> 5, jj = r & 31;
      wlds[r*LDS_LD + k] = (f16)Whh0[(g*HD + s0 + jj)*HD + k];
    }
  } else {
    const int bid2 = bid - 128;
    const int mg = bid2 >> 5, ng = bid2 & 31;
    Mbase = mg * 64; s0 = ng * 16;
    for (int idx = tid; idx < 96*512; idx += NTHR) {
      int r = idx >> 9, k = idx & 511;
      const float* Wsrc = (r < 48) ? Wih1 : Whh1;
      int rr = (r < 48) ? r : r - 48;
      int g = rr >> 4, jj = rr & 15;
      wlds[r*LDS_LD + k] = (f16)Wsrc[(g*HD + s0 + jj)*HD + k];
    }
  }

  // ---------------- per-thread constants ------------------------------------
  float wi_r=0, wi_z=0, wi_n=0, bi_r, bi_z, bi_n, bh_r, bh_z, bh_n;
  float woutj=0, boutv=0;
  int jcol, mf;
  if (isA) {
    mf = w >> 1; const int jh = w & 1;
    jcol = s0 + jh*16 + l16;
    wi_r = Wih0[jcol]; wi_z = Wih0[HD + jcol]; wi_n = Wih0[2*HD + jcol];
    bi_r = bih0[jcol]; bi_z = bih0[HD + jcol]; bi_n = bih0[2*HD + jcol];
    bh_r = bhh0[jcol]; bh_z = bhh0[HD + jcol]; bh_n = bhh0[2*HD + jcol];
  } else {
    mf = w; jcol = s0 + l16;
    bi_r = bih1[jcol]; bi_z = bih1[HD + jcol]; bi_n = bih1[2*HD + jcol];
    bh_r = bhh1[jcol]; bh_z = bhh1[HD + jcol]; bh_n = bhh1[2*HD + jcol];
    woutj = Wout[jcol]; boutv = boutp[0];
  }

  uint32 gen = 1;
  gbar(base16, baseRel, gen); gen++;   // scale, h bufs, y_acc, LDS weights ready

  // A-threads: preload scale for their 4 output rows (stable after barrier 1)
  float scl[4] = {1.f,1.f,1.f,1.f};
  if (isA) {
    const int bb = Mbase + mf*16 + quad*4;
    #pragma unroll
    for (int reg = 0; reg < 4; ++reg) scl[reg] = ld_f32_dc(&g_scale[bb + reg]);
  }

  // ---------------- interval loop -------------------------------------------
  for (int i = 0; i <= 638; ++i) {
    if (isA) {
      int sA = -1;
      if (i <= 511) sA = i;
      else if (i >= 513 && ((i-513)&1) == 0 && (i-513)/2 <= 62)
        sA = 512 + (i-513)/2;
      if (sA >= 0) {
        const f16* hrd = &g_h0[sA & 1][0][0];
        f16*       hwr = &g_h0[(sA+1) & 1][0][0];
        const int b0 = Mbase + mf*16 + quad*4;
        // prefetch epilogue operands (L3 latency hides under MFMA loop)
        float hold[4], xv[4];
        #pragma unroll
        for (int reg = 0; reg < 4; ++reg) {
          hold[reg] = ld_f16_dc(&hrd[(size_t)(b0+reg)*HD + jcol]);
          xv[reg] = (sA < 512) ? (ctx[(b0+reg)*CTXL + sA] / scl[reg])
                               : ld_f32_dc(&g_yacc[sA-512][b0+reg]);
        }
        floatx4 ar = {0.f,0.f,0.f,0.f}, az = ar, an_ = ar;
        const int arow = Mbase + mf*16 + l16;
        const f16* aptr = hrd + (size_t)arow*HD + quad*8;
        const f16* b_r  = wlds + (size_t)((w&1)*16 + l16)*LDS_LD + quad*8;
        #pragma unroll 4
        for (int kc = 0; kc < 16; ++kc) {
          half8 a  = ld_half8_dc(aptr + kc*32);
          half8 vr = *(const half8*)(b_r + kc*32);
          half8 vz = *(const half8*)(b_r + 32*LDS_LD + kc*32);
          half8 vn = *(const half8*)(b_r + 64*LDS_LD + kc*32);
          ar  = __builtin_amdgcn_mfma_f32_16x16x32_f16(a, vr, ar,  0,0,0);
          az  = __builtin_amdgcn_mfma_f32_16x16x32_f16(a, vz, az,  0,0,0);
          an_ = __builtin_amdgcn_mfma_f32_16x16x32_f16(a, vn, an_, 0,0,0);
        }
        #pragma unroll
        for (int reg = 0; reg < 4; ++reg) {
          float hgr = ar[reg] + bh_r, hgz = az[reg] + bh_z, hgn = an_[reg] + bh_n;
          float rg  = sigm(fmaf(xv[reg], wi_r, bi_r) + hgr);
          float zg  = sigm(fmaf(xv[reg], wi_z, bi_z) + hgz);
          float ng_ = tanh_(fmaf(xv[reg], wi_n, bi_n) + rg*hgn);
          st_f16_dc(&hwr[(size_t)(b0+reg)*HD + jcol], (1.f - zg)*ng_ + zg*hold[reg]);
        }
      }
    } else {
      int sB = -1;
      if (i >= 1 && i <= 512) sB = i - 1;
      else if (i >= 514 && ((i-514)&1) == 0 && (i-514)/2 <= 62)
        sB = 512 + (i-514)/2;
      if (sB >= 0) {
        const f16* h0rd = &g_h0[(sB+1) & 1][0][0];   // layer-0 output of step sB
        const f16* h1rd = &g_h1[sB & 1][0][0];
        f16*       h1wr = &g_h1[(sB+1) & 1][0][0];
        const int b0 = Mbase + mf*16 + quad*4;
        float hold[4];
        #pragma unroll
        for (int reg = 0; reg < 4; ++reg)
          hold[reg] = ld_f16_dc(&h1rd[(size_t)(b0+reg)*HD + jcol]);
        floatx4 xr = {0.f,0.f,0.f,0.f}, xz = xr, xn = xr, hr = xr, hz = xr, hn = xr;
        const int arow = Mbase + mf*16 + l16;
        const f16* a0p = h0rd + (size_t)arow*HD + quad*8;
        const f16* a1p = h1rd + (size_t)arow*HD + quad*8;
        const f16* bw  = wlds + (size_t)l16*LDS_LD + quad*8;
        #pragma unroll 4
        for (int kc = 0; kc < 16; ++kc) {
          half8 a0 = ld_half8_dc(a0p + kc*32);
          half8 a1 = ld_half8_dc(a1p + kc*32);
          half8 v;
          v = *(const half8*)(bw +             kc*32); xr = __builtin_amdgcn_mfma_f32_16x16x32_f16(a0, v, xr, 0,0,0);
          v = *(const half8*)(bw + 16*LDS_LD + kc*32); xz = __builtin_amdgcn_mfma_f32_16x16x32_f16(a0, v, xz, 0,0,0);
          v = *(const half8*)(bw + 32*LDS_LD + kc*32); xn = __builtin_amdgcn_mfma_f32_16x16x32_f16(a0, v, xn, 0,0,0);
          v = *(const half8*)(bw + 48*LDS_LD + kc*32); hr = __builtin_amdgcn_mfma_f32_16x16x32_f16(a1, v, hr, 0,0,0);
          v = *(const half8*)(bw + 64*LDS_LD + kc*32); hz = __builtin_amdgcn_mfma_f32_16x16x32_f16(a1, v, hz, 0,0,0);
          v = *(const half8*)(bw + 80*LDS_LD + kc*32); hn = __builtin_amdgcn_mfma_f32_16x16x32_f16(a1, v, hn, 0,0,0);
        }
        #pragma unroll
        for (int reg = 0; reg < 4; ++reg) {
          const int b = b0 + reg;
          float rg  = sigm(xr[reg] + bi_r + hr[reg] + bh_r);
          float zg  = sigm(xz[reg] + bi_z + hz[reg] + bh_z);
          float ng_ = tanh_(xn[reg] + bi_n + rg*(hn[reg] + bh_n));
          float hnew = (1.f - zg)*ng_ + zg*hold[reg];
          st_f16_dc(&h1wr[(size_t)b*HD + jcol], hnew);
          if (sB >= 511) {                       // emit forecast partials
            float c = hnew * woutj;
            c += __shfl_xor(c, 1, 64); c += __shfl_xor(c, 2, 64);
            c += __shfl_xor(c, 4, 64); c += __shfl_xor(c, 8, 64);
            if (l16 == 0) {
              if (s0 == 0) c += boutv;           // bias exactly once per row
              atomicAdd(&g_yacc[sB-511][b], c);  // device-scope, coherent path
            }
          }
        }
      }
    }
    gbar(base16, baseRel, gen); gen++;
  }

  // ---------------- epoch advance + output ----------------------------------
  if (bid == 0 && tid == 0)
    st_u32_dc(&g_epoch, E + 1u);

  if (bid < NPRED) {
    const int p = bid;
    for (int b = tid; b < NBAT; b += NTHR)
      out[b*NPRED + p] = ld_f32_dc(&g_yacc[p][b]) * ld_f32_dc(&g_scale[b]);
  }
}

extern "C" void kernel_launch(void* const* d_in, const int* in_sizes, int n_in,
                              void* d_out, int out_size, void* d_ws, size_t ws_size,
                              hipStream_t stream) {
  const float* ctx   = (const float*)d_in[0];
  const float* Wih0  = (const float*)d_in[1];
  const float* Whh0  = (const float*)d_in[2];
  const float* bih0  = (const float*)d_in[3];
  const float* bhh0  = (const float*)d_in[4];
  const float* Wih1  = (const float*)d_in[5];
  const float* Whh1  = (const float*)d_in[6];
  const float* bih1  = (const float*)d_in[7];
  const float* bhh1  = (const float*)d_in[8];
  const float* Wout  = (const float*)d_in[9];
  const float* boutp = (const float*)d_in[10];
  float* out = (float*)d_out;

  hipFuncSetAttribute(reinterpret_cast<const void*>(rnn_persist),
                      hipFuncAttributeMaxDynamicSharedMemorySize, LDS_BYTES);

  void* params[] = {
    (void*)&ctx, (void*)&Wih0, (void*)&Whh0, (void*)&bih0, (void*)&bhh0,
    (void*)&Wih1, (void*)&Whh1, (void*)&bih1, (void*)&bhh1,
    (void*)&Wout, (void*)&boutp, (void*)&out
  };
  hipLaunchCooperativeKernel(reinterpret_cast<void*>(rnn_persist),
                             dim3(NBLK), dim3(NTHR), params, LDS_BYTES, stream);
}